// Round 2
// baseline (24810.434 us; speedup 1.0000x reference)
//
#include <hip/hip_runtime.h>
#include <math.h>

// SkipLSTM: B=128, S=512, IN=HS=1024, 4H=4096.
// Round 3: identical to round-2 pipelined design (double-buffered gemm core,
// 4 waves/block, rebalanced grids), with A1a/A1b ALIASED onto A0a/A0b so the
// workspace layout is byte-identical to the harness-verified round-1 kernel
// (cell0 consumes A0a/A0b before phase2 overwrites them — stream-ordered safe).
// Split-bf16 (Markidis 3-term) MFMA via v_mfma_f32_32x32x16_bf16 with
// pre-swizzled operands (layouts unchanged from the verified round-1 kernel).
#define BB 128
#define SS 512
#define HSZ 1024
#define FH 4096

typedef __attribute__((ext_vector_type(8))) short short8;
typedef __attribute__((ext_vector_type(8))) unsigned short ushort8;
typedef __attribute__((ext_vector_type(16))) float f32x16;

#define APL 131072L   // A-plane elems (128x1024) per bf16 plane
#define BPL 4194304L  // B-plane elems (1024x4096) per bf16 plane
#define LDSH 12288    // ushorts per LDS buffer (A 8192 + B 4096)

__device__ __forceinline__ unsigned short f2bf(float f) {
    unsigned u = __float_as_uint(f);
    u += 0x7FFFu + ((u >> 16) & 1u);
    return (unsigned short)(u >> 16);
}
__device__ __forceinline__ float bf2f(unsigned short h) {
    return __uint_as_float(((unsigned)h) << 16);
}
__device__ __forceinline__ float sigm_(float x) { return 1.0f / (1.0f + expf(-x)); }

__device__ __forceinline__ void gll16(const void* g, void* l) {
    __builtin_amdgcn_global_load_lds((const __attribute__((address_space(1))) unsigned int*)g,
                                     (__attribute__((address_space(3))) unsigned int*)l, 16, 0, 0);
}

// ---------------- pipelined split-bf16 MFMA GEMM core ----------------
// Block: 256 threads = 4 waves. Block tile 128(M) x 64(N). Wave w owns row-tile
// rt = w (rows 32w..32w+31).
// A swizzled global layout: [kc(64)][rt(4)][lane(64)][j(8)]  (hi plane, lo at +APL)
//   element: m = rt*32 + (lane&31), k = kc*16 + (lane>>5)*8 + j
// B swizzled global layout: [nt(128)][kc(64)][lane(64)][j(8)] (hi plane, lo at +BPL)
//   element: n = nt*32 + (lane&31), k = kc*16 + (lane>>5)*8 + j
// LDS buffer (one K=32 iter): A [pl(2)][c(2)][rt(4)][lane][8] = 16KB,
//                             B [pl(2)][c(2)][t(2)][lane][8] = 8KB.
// Staging split: wave w stages plane pl=w>>1, K-half c=w&1 (6 gll16/wave/iter).
// LDS dest pointers are wave-uniform (global_load_lds writes base + lane*16B).

__device__ __forceinline__ void gemm_stage(const unsigned short* __restrict__ Ah,
                                           const unsigned short* __restrict__ Bh,
                                           int nt0, int i, unsigned short* lds,
                                           int wave, int lane)
{
    const int pl = wave >> 1, c = wave & 1;
    const unsigned short* Ab = Ah + (long)pl * APL + ((long)(2 * i + c) * 4) * 512 + lane * 8;
    unsigned short* La = lds + ((pl * 2 + c) * 4) * 512;
#pragma unroll
    for (int rt = 0; rt < 4; ++rt)
        gll16(Ab + rt * 512, La + rt * 512);
    const unsigned short* Bb = Bh + (long)pl * BPL + lane * 8;
#pragma unroll
    for (int t = 0; t < 2; ++t)
        gll16(Bb + ((long)(nt0 + t) * 64 + 2 * i + c) * 512,
              lds + 8192 + ((pl * 2 + c) * 2 + t) * 512);
}

__device__ __forceinline__ void gemm_compute(const unsigned short* lds, f32x16 acc[2],
                                             int wave, int lane)
{
#pragma unroll
    for (int c = 0; c < 2; ++c) {
        const short8 ah = *(const short8*)(lds + (c * 4 + wave) * 512 + lane * 8);
        const short8 al = *(const short8*)(lds + 4096 + (c * 4 + wave) * 512 + lane * 8);
        short8 bh[2], bl[2];
#pragma unroll
        for (int t = 0; t < 2; ++t) {
            bh[t] = *(const short8*)(lds + 8192 + (c * 2 + t) * 512 + lane * 8);
            bl[t] = *(const short8*)(lds + 8192 + ((2 + c) * 2 + t) * 512 + lane * 8);
        }
#pragma unroll
        for (int t = 0; t < 2; ++t) {
            acc[t] = __builtin_amdgcn_mfma_f32_32x32x16_bf16(ah, bh[t], acc[t], 0, 0, 0);
            acc[t] = __builtin_amdgcn_mfma_f32_32x32x16_bf16(ah, bl[t], acc[t], 0, 0, 0);
            acc[t] = __builtin_amdgcn_mfma_f32_32x32x16_bf16(al, bh[t], acc[t], 0, 0, 0);
        }
    }
}

// Double-buffered main loop: stage(i+1) is issued BEFORE compute(i); the single
// __syncthreads per iter drains vmcnt (stage i+1 done, overlapped with compute i)
// and protects buffer reuse.
__device__ __forceinline__ void gemm_pipe(const unsigned short* __restrict__ Ah,
                                          const unsigned short* __restrict__ Bh,
                                          int nt0, int i0, int n, f32x16 acc[2],
                                          unsigned short* lds, int wave, int lane)
{
    gemm_stage(Ah, Bh, nt0, i0, lds, wave, lane);
    __syncthreads();
    for (int i = 0; i < n; ++i) {
        unsigned short* cur = lds + (i & 1) * LDSH;
        unsigned short* nxt = lds + ((i + 1) & 1) * LDSH;
        if (i + 1 < n) gemm_stage(Ah, Bh, nt0, i0 + i + 1, nxt, wave, lane);
        gemm_compute(cur, acc, wave, lane);
        __syncthreads();
    }
}

__device__ __forceinline__ void cwrite(float* __restrict__ C, const f32x16 acc[2],
                                       int n0, int wave, int lane)
{
#pragma unroll
    for (int t = 0; t < 2; ++t)
#pragma unroll
        for (int q = 0; q < 16; ++q) {
            const int m = 32 * wave + (q & 3) + 8 * (q >> 2) + 4 * (lane >> 5);
            const int n = n0 + t * 32 + (lane & 31);
            C[(long)m * FH + n] = acc[t][q];
        }
}

// phase1: 192 blocks. job 0: A0a = x_t@U0 ; job 1: A0b = h0@V0 ; job 2: T1 = h1@V1
__global__ __launch_bounds__(256) void phase1(
    const unsigned short* __restrict__ xsw,  const unsigned short* __restrict__ U0sw,
    const unsigned short* __restrict__ h0sw, const unsigned short* __restrict__ V0sw,
    const unsigned short* __restrict__ h1sw, const unsigned short* __restrict__ V1sw,
    float* __restrict__ A0a, float* __restrict__ A0b, float* __restrict__ T1)
{
    __shared__ unsigned short lds[2 * LDSH];
    const int tid = threadIdx.x, wave = tid >> 6, lane = tid & 63;
    const int nblk = blockIdx.x & 63, job = blockIdx.x >> 6;
    const int nt0 = nblk * 2, n0 = nblk * 64;
    const unsigned short* Ah = (job == 0) ? xsw  : (job == 1) ? h0sw : h1sw;
    const unsigned short* Bh = (job == 0) ? U0sw : (job == 1) ? V0sw : V1sw;
    float* C = (job == 0) ? A0a : (job == 1) ? A0b : T1;
    f32x16 acc[2];
#pragma unroll
    for (int t = 0; t < 2; ++t)
#pragma unroll
        for (int q = 0; q < 16; ++q) acc[t][q] = 0.0f;
    gemm_pipe(Ah, Bh, nt0, 0, 32, acc, lds, wave, lane);
    cwrite(C, acc, n0, wave, lane);
}

// phase2: 128 blocks, K-split. ks 0: A1a = h0@U1[k<512] ; ks 1: A1b = h0@U1[k>=512]
__global__ __launch_bounds__(256) void phase2(
    const unsigned short* __restrict__ h0sw, const unsigned short* __restrict__ U1sw,
    float* __restrict__ A1a, float* __restrict__ A1b)
{
    __shared__ unsigned short lds[2 * LDSH];
    const int tid = threadIdx.x, wave = tid >> 6, lane = tid & 63;
    const int nblk = blockIdx.x & 63, ks = blockIdx.x >> 6;
    const int nt0 = nblk * 2, n0 = nblk * 64;
    f32x16 acc[2];
#pragma unroll
    for (int t = 0; t < 2; ++t)
#pragma unroll
        for (int q = 0; q < 16; ++q) acc[t][q] = 0.0f;
    gemm_pipe(h0sw, U1sw, nt0, ks * 16, 16, acc, lds, wave, lane);
    cwrite(ks ? A1b : A1a, acc, n0, wave, lane);
}

// split one fp32 value-row chunk into swizzled hi/lo planes (A layout)
__device__ __forceinline__ void split_to_Asw(const float v[8], unsigned short* __restrict__ sw,
                                             int b, int k8)
{
    ushort8 hh, ll;
#pragma unroll
    for (int j = 0; j < 8; ++j) {
        const unsigned short h = f2bf(v[j]);
        hh[j] = h;
        ll[j] = f2bf(v[j] - bf2f(h));
    }
    const int kc = k8 >> 1, half = k8 & 1;
    const int l = half * 32 + (b & 31), rt = b >> 5;
    const long o = ((long)(kc * 4 + rt) * 64 + l) * 8;
    *(ushort8*)(sw + o) = hh;
    *(ushort8*)(sw + APL + o) = ll;
}

// cell0: gates from A0a+A0b+b0 -> c0, h0 (fp32) + h0sw. 128 blocks x 128 thr.
__global__ __launch_bounds__(128) void cell0(
    const float* __restrict__ A0a, const float* __restrict__ A0b,
    const float* __restrict__ b0,
    float* __restrict__ c0, float* __restrict__ h0,
    unsigned short* __restrict__ h0sw, const float* __restrict__ u_rnd)
{
    const int b = blockIdx.x, k8 = threadIdx.x;
    const long gb = (long)b * FH + k8 * 8;
    const long sb = (long)b * HSZ + k8 * 8;
    const float u = u_rnd[b];
    float hn[8];
#pragma unroll
    for (int half = 0; half < 2; ++half) {
        const int j0 = half * 4;
        const float4 aia = *(const float4*)(A0a + gb + j0);
        const float4 aib = *(const float4*)(A0b + gb + j0);
        const float4 afa = *(const float4*)(A0a + gb + HSZ + j0);
        const float4 afb = *(const float4*)(A0b + gb + HSZ + j0);
        const float4 aga = *(const float4*)(A0a + gb + 2 * HSZ + j0);
        const float4 agb = *(const float4*)(A0b + gb + 2 * HSZ + j0);
        const float4 aoa = *(const float4*)(A0a + gb + 3 * HSZ + j0);
        const float4 aob = *(const float4*)(A0b + gb + 3 * HSZ + j0);
        const float4 bi = *(const float4*)(b0 + k8 * 8 + j0);
        const float4 bf = *(const float4*)(b0 + HSZ + k8 * 8 + j0);
        const float4 bg = *(const float4*)(b0 + 2 * HSZ + k8 * 8 + j0);
        const float4 bo = *(const float4*)(b0 + 3 * HSZ + k8 * 8 + j0);
        float4 cv = *(const float4*)(c0 + sb + j0);
        const float4 hv = *(const float4*)(h0 + sb + j0);
        float4 cn, hq;
#pragma unroll
        for (int j = 0; j < 4; ++j) {
            const float I = sigm_(((const float*)&aia)[j] + ((const float*)&aib)[j] + ((const float*)&bi)[j]);
            const float F = sigm_(((const float*)&afa)[j] + ((const float*)&afb)[j] + ((const float*)&bf)[j]);
            const float G = tanhf(((const float*)&aga)[j] + ((const float*)&agb)[j] + ((const float*)&bg)[j]);
            const float O = sigm_(((const float*)&aoa)[j] + ((const float*)&aob)[j] + ((const float*)&bo)[j]);
            const float c = fmaf(F, ((const float*)&cv)[j], I * G);
            ((float*)&cn)[j] = c;
            const float h = u * (O * tanhf(c)) + (1.0f - u) * ((const float*)&hv)[j];
            ((float*)&hq)[j] = h;
            hn[j0 + j] = h;
        }
        *(float4*)(c0 + sb + j0) = cn;
        *(float4*)(h0 + sb + j0) = hq;
    }
    split_to_Asw(hn, h0sw, b, k8);
}

// cell1: gates from A1a+A1b+T1+b1 -> c1, h1, out, h1sw; fused skip-dot + u
// update (blocks [0,128)); blocks [128,256) swizzle x_{t+1}.
__global__ __launch_bounds__(128) void cell1(
    const float* __restrict__ A1a, const float* __restrict__ A1b,
    const float* __restrict__ T1, const float* __restrict__ b1,
    float* __restrict__ c1, float* __restrict__ h1,
    unsigned short* __restrict__ h1sw,
    float* __restrict__ u_t, float* __restrict__ u_rnd,
    const float* __restrict__ skip_w, const float* __restrict__ skip_b,
    float* __restrict__ out, int t,
    const float* __restrict__ x, unsigned short* __restrict__ xsw)
{
    __shared__ float red[2];
    if (blockIdx.x < 128) {
        const int b = blockIdx.x, k8 = threadIdx.x;
        const long gb = (long)b * FH + k8 * 8;
        const long sb = (long)b * HSZ + k8 * 8;
        const float u = u_rnd[b];
        const float ut_old = u_t[b];
        float hn[8];
        float part = 0.0f;
#pragma unroll
        for (int half = 0; half < 2; ++half) {
            const int j0 = half * 4;
            const float4 aia = *(const float4*)(A1a + gb + j0);
            const float4 aib = *(const float4*)(A1b + gb + j0);
            const float4 ait = *(const float4*)(T1 + gb + j0);
            const float4 afa = *(const float4*)(A1a + gb + HSZ + j0);
            const float4 afb = *(const float4*)(A1b + gb + HSZ + j0);
            const float4 aft = *(const float4*)(T1 + gb + HSZ + j0);
            const float4 aga = *(const float4*)(A1a + gb + 2 * HSZ + j0);
            const float4 agb = *(const float4*)(A1b + gb + 2 * HSZ + j0);
            const float4 agt = *(const float4*)(T1 + gb + 2 * HSZ + j0);
            const float4 aoa = *(const float4*)(A1a + gb + 3 * HSZ + j0);
            const float4 aob = *(const float4*)(A1b + gb + 3 * HSZ + j0);
            const float4 aot = *(const float4*)(T1 + gb + 3 * HSZ + j0);
            const float4 bi = *(const float4*)(b1 + k8 * 8 + j0);
            const float4 bf = *(const float4*)(b1 + HSZ + k8 * 8 + j0);
            const float4 bg = *(const float4*)(b1 + 2 * HSZ + k8 * 8 + j0);
            const float4 bo = *(const float4*)(b1 + 3 * HSZ + k8 * 8 + j0);
            float4 cv = *(const float4*)(c1 + sb + j0);
            const float4 hv = *(const float4*)(h1 + sb + j0);
            const float4 sw4 = *(const float4*)(skip_w + k8 * 8 + j0);
            float4 cn, hq;
#pragma unroll
            for (int j = 0; j < 4; ++j) {
                const float I = sigm_(((const float*)&aia)[j] + ((const float*)&aib)[j] + ((const float*)&ait)[j] + ((const float*)&bi)[j]);
                const float F = sigm_(((const float*)&afa)[j] + ((const float*)&afb)[j] + ((const float*)&aft)[j] + ((const float*)&bf)[j]);
                const float G = tanhf(((const float*)&aga)[j] + ((const float*)&agb)[j] + ((const float*)&agt)[j] + ((const float*)&bg)[j]);
                const float O = sigm_(((const float*)&aoa)[j] + ((const float*)&aob)[j] + ((const float*)&aot)[j] + ((const float*)&bo)[j]);
                const float c = fmaf(F, ((const float*)&cv)[j], I * G);
                ((float*)&cn)[j] = c;
                part = fmaf(c, ((const float*)&sw4)[j], part);
                const float h = u * (O * tanhf(c)) + (1.0f - u) * ((const float*)&hv)[j];
                ((float*)&hq)[j] = h;
                hn[j0 + j] = h;
            }
            *(float4*)(c1 + sb + j0) = cn;
            *(float4*)(h1 + sb + j0) = hq;
            *(float4*)(out + ((long)b * SS + t) * HSZ + k8 * 8 + j0) = hq;
        }
        split_to_Asw(hn, h1sw, b, k8);
#pragma unroll
        for (int off = 32; off > 0; off >>= 1) part += __shfl_down(part, off, 64);
        const int wave = threadIdx.x >> 6;
        if ((threadIdx.x & 63) == 0) red[wave] = part;
        __syncthreads();
        if (threadIdx.x == 0) {
            const float z = red[0] + red[1];
            const float cu = sigm_(z + skip_b[0]);
            const float nut = u * cu + (1.0f - u) * (ut_old + fminf(cu, 1.0f - ut_old));
            u_t[b] = nut;
            u_rnd[b] = rintf(nut);
        }
    } else {
        // swizzle x for step t+1
        if (t + 1 >= SS) return;
        const int idx = (blockIdx.x - 128) * 128 + threadIdx.x;
        const int b = idx >> 7, k8 = idx & 127;
        const float* xr = x + ((long)b * SS + (t + 1)) * HSZ + k8 * 8;
        float v[8];
        const float4 v0 = *(const float4*)(xr);
        const float4 v1 = *(const float4*)(xr + 4);
#pragma unroll
        for (int j = 0; j < 4; ++j) { v[j] = ((const float*)&v0)[j]; v[4 + j] = ((const float*)&v1)[j]; }
        split_to_Asw(v, xsw, b, k8);
    }
}

// weight split+swizzle: one thread per (w, nt, kc, lane)
__global__ __launch_bounds__(256) void prep_w(
    const float* __restrict__ U0, const float* __restrict__ V0,
    const float* __restrict__ U1, const float* __restrict__ V1,
    unsigned short* __restrict__ U0sw, unsigned short* __restrict__ V0sw,
    unsigned short* __restrict__ U1sw, unsigned short* __restrict__ V1sw)
{
    const long gid = (long)blockIdx.x * 256 + threadIdx.x;  // 4 * 524288
    const int w = (int)(gid >> 19);
    const int r = (int)(gid & 524287);                      // nt*4096 + kc*64 + l
    const int nt = r >> 12;
    const int kc = (r >> 6) & 63;
    const int l = r & 63;
    const float* W = (w == 0) ? U0 : (w == 1) ? V0 : (w == 2) ? U1 : V1;
    unsigned short* O = (w == 0) ? U0sw : (w == 1) ? V0sw : (w == 2) ? U1sw : V1sw;
    const int n = nt * 32 + (l & 31);
    const int k0 = kc * 16 + (l >> 5) * 8;
    ushort8 hh, ll;
#pragma unroll
    for (int j = 0; j < 8; ++j) {
        const float f = W[(long)(k0 + j) * FH + n];
        const unsigned short h = f2bf(f);
        hh[j] = h;
        ll[j] = f2bf(f - bf2f(h));
    }
    const long ob = (long)r * 8;
    *(ushort8*)(O + ob) = hh;
    *(ushort8*)(O + BPL + ob) = ll;
}

// init: zero fp32 states, zero h0sw/h1sw, u=1, swizzle x_0
__global__ __launch_bounds__(256) void init_k(
    float* __restrict__ states, float* __restrict__ swz_f,
    float* __restrict__ u_t, float* __restrict__ u_rnd,
    const float* __restrict__ x, unsigned short* __restrict__ xsw)
{
    const int blk = blockIdx.x;
    const float4 z = {0.0f, 0.0f, 0.0f, 0.0f};
    if (blk < 512) {
        *(float4*)(states + ((long)blk * 256 + threadIdx.x) * 4) = z;
    } else if (blk < 768) {
        *(float4*)(swz_f + ((long)(blk - 512) * 256 + threadIdx.x) * 4) = z;
    } else {
        if (blk == 768 && threadIdx.x < 128) { u_t[threadIdx.x] = 1.0f; u_rnd[threadIdx.x] = 1.0f; }
        const int idx = (blk - 768) * 256 + threadIdx.x;
        const int b = idx >> 7, k8 = idx & 127;
        const float* xr = x + (long)b * SS * HSZ + k8 * 8;
        float v[8];
        const float4 v0 = *(const float4*)(xr);
        const float4 v1 = *(const float4*)(xr + 4);
#pragma unroll
        for (int j = 0; j < 4; ++j) { v[j] = ((const float*)&v0)[j]; v[4 + j] = ((const float*)&v1)[j]; }
        split_to_Asw(v, xsw, b, k8);
    }
}

extern "C" void kernel_launch(void* const* d_in, const int* in_sizes, int n_in,
                              void* d_out, int out_size, void* d_ws, size_t ws_size,
                              hipStream_t stream)
{
    const float* x      = (const float*)d_in[0];
    const float* U0     = (const float*)d_in[1];
    const float* V0     = (const float*)d_in[2];
    const float* b0     = (const float*)d_in[3];
    const float* U1     = (const float*)d_in[4];
    const float* V1     = (const float*)d_in[5];
    const float* b1     = (const float*)d_in[6];
    const float* skip_w = (const float*)d_in[7];
    const float* skip_b = (const float*)d_in[8];
    float* out = (float*)d_out;

    float* ws = (float*)d_ws;
    float* states = ws;                 // h0,c0,h1,c1 : 4*131072 floats
    float* h0 = ws;
    float* c0 = ws + 131072;
    float* h1 = ws + 262144;
    float* c1 = ws + 393216;
    float* A0a = ws + 524288;           // each 128x4096 fp32
    float* A0b = ws + 1048576;
    float* T1  = ws + 1572864;
    // A1a/A1b alias A0a/A0b: cell0 fully consumes A0a/A0b before phase2 writes
    // (stream-ordered), so the round-1 workspace footprint is preserved.
    float* A1a = A0a;
    float* A1b = A0b;
    float* u_t   = ws + 2097152;        // 128
    float* u_rnd = ws + 2097280;        // 128
    unsigned short* usbase = (unsigned short*)(ws + 2097664);  // 16B-aligned
    unsigned short* xsw  = usbase;                  // 2*APL ushorts
    unsigned short* h0sw = usbase + 262144;
    unsigned short* h1sw = usbase + 524288;
    unsigned short* U0sw = usbase + 786432;         // each 2*BPL ushorts
    unsigned short* V0sw = U0sw + 8388608;
    unsigned short* U1sw = V0sw + 8388608;
    unsigned short* V1sw = U1sw + 8388608;

    prep_w<<<8192, 256, 0, stream>>>(U0, V0, U1, V1, U0sw, V0sw, U1sw, V1sw);
    init_k<<<832, 256, 0, stream>>>(states, (float*)h0sw /* h0sw+h1sw zeroed */,
                                    u_t, u_rnd, x, xsw);

    for (int t = 0; t < SS; ++t) {
        phase1<<<192, 256, 0, stream>>>(xsw, U0sw, h0sw, V0sw, h1sw, V1sw, A0a, A0b, T1);
        cell0<<<128, 128, 0, stream>>>(A0a, A0b, b0, c0, h0, h0sw, u_rnd);
        phase2<<<128, 256, 0, stream>>>(h0sw, U1sw, A1a, A1b);
        cell1<<<256, 128, 0, stream>>>(A1a, A1b, T1, b1, c1, h1, h1sw, u_t, u_rnd,
                                       skip_w, skip_b, out, t, x, xsw);
    }
}

// Round 5
// 22727.194 us; speedup vs baseline: 1.0917x; 1.0917x over previous
//
#include <hip/hip_runtime.h>
#include <math.h>

// SkipLSTM: B=128, S=512, IN=HS=1024, 4H=4096.
// Round 6 (= round-4/5 resubmit; never benched due to GPU acquisition timeouts):
// DEPTH-3 counted-vmcnt pipeline in gemm_pipe (T3/T4 pattern): never drain
// vmcnt in the steady-state loop; raw s_barrier pair per iter (B1 = stage
// landed, B2 = buffer reads done before reuse). Everything else identical to
// the harness-verified round-3 kernel (24.8 ms): split-bf16 (Markidis 3-term)
// MFMA via v_mfma_f32_32x32x16_bf16, pre-swizzled operands, rebalanced grids,
// A1a/A1b aliased onto A0a/A0b.
#define BB 128
#define SS 512
#define HSZ 1024
#define FH 4096

typedef __attribute__((ext_vector_type(8))) short short8;
typedef __attribute__((ext_vector_type(8))) unsigned short ushort8;
typedef __attribute__((ext_vector_type(16))) float f32x16;

#define APL 131072L   // A-plane elems (128x1024) per bf16 plane
#define BPL 4194304L  // B-plane elems (1024x4096) per bf16 plane
#define LDSH 12288    // ushorts per LDS buffer (A 8192 + B 4096)
#define DEPTH 3       // pipeline depth (3 x 24KB = 72KB LDS)

__device__ __forceinline__ unsigned short f2bf(float f) {
    unsigned u = __float_as_uint(f);
    u += 0x7FFFu + ((u >> 16) & 1u);
    return (unsigned short)(u >> 16);
}
__device__ __forceinline__ float bf2f(unsigned short h) {
    return __uint_as_float(((unsigned)h) << 16);
}
__device__ __forceinline__ float sigm_(float x) { return 1.0f / (1.0f + expf(-x)); }

__device__ __forceinline__ void gll16(const void* g, void* l) {
    __builtin_amdgcn_global_load_lds((const __attribute__((address_space(1))) unsigned int*)g,
                                     (__attribute__((address_space(3))) unsigned int*)l, 16, 0, 0);
}

// ---------------- pipelined split-bf16 MFMA GEMM core ----------------
// Block: 256 threads = 4 waves. Block tile 128(M) x 64(N). Wave w owns row-tile
// rt = w (rows 32w..32w+31).
// A swizzled global layout: [kc(64)][rt(4)][lane(64)][j(8)]  (hi plane, lo at +APL)
//   element: m = rt*32 + (lane&31), k = kc*16 + (lane>>5)*8 + j
// B swizzled global layout: [nt(128)][kc(64)][lane(64)][j(8)] (hi plane, lo at +BPL)
//   element: n = nt*32 + (lane&31), k = kc*16 + (lane>>5)*8 + j
// LDS buffer (one K=32 iter): A [pl(2)][c(2)][rt(4)][lane][8] = 16KB,
//                             B [pl(2)][c(2)][t(2)][lane][8] = 8KB.
// Staging split: wave w stages plane pl=w>>1, K-half c=w&1 (6 gll16/wave/iter).
// LDS dest pointers are wave-uniform (global_load_lds writes base + lane*16B).

__device__ __forceinline__ void gemm_stage(const unsigned short* __restrict__ Ah,
                                           const unsigned short* __restrict__ Bh,
                                           int nt0, int i, unsigned short* lds,
                                           int wave, int lane)
{
    const int pl = wave >> 1, c = wave & 1;
    const unsigned short* Ab = Ah + (long)pl * APL + ((long)(2 * i + c) * 4) * 512 + lane * 8;
    unsigned short* La = lds + ((pl * 2 + c) * 4) * 512;
#pragma unroll
    for (int rt = 0; rt < 4; ++rt)
        gll16(Ab + rt * 512, La + rt * 512);
    const unsigned short* Bb = Bh + (long)pl * BPL + lane * 8;
#pragma unroll
    for (int t = 0; t < 2; ++t)
        gll16(Bb + ((long)(nt0 + t) * 64 + 2 * i + c) * 512,
              lds + 8192 + ((pl * 2 + c) * 2 + t) * 512);
}

// all MFMA fragments for one K=32 iter (12 x ds_read_b128 per wave; fully
// static indexing so everything stays in registers)
struct Frags {
    short8 ah[2], al[2], bh[2][2], bl[2][2];
};

__device__ __forceinline__ void frag_read(const unsigned short* lds, Frags& f,
                                          int wave, int lane)
{
#pragma unroll
    for (int c = 0; c < 2; ++c) {
        f.ah[c] = *(const short8*)(lds + (c * 4 + wave) * 512 + lane * 8);
        f.al[c] = *(const short8*)(lds + 4096 + (c * 4 + wave) * 512 + lane * 8);
#pragma unroll
        for (int t = 0; t < 2; ++t) {
            f.bh[c][t] = *(const short8*)(lds + 8192 + (c * 2 + t) * 512 + lane * 8);
            f.bl[c][t] = *(const short8*)(lds + 8192 + ((2 + c) * 2 + t) * 512 + lane * 8);
        }
    }
}

__device__ __forceinline__ void frag_mfma(const Frags& f, f32x16 acc[2])
{
#pragma unroll
    for (int c = 0; c < 2; ++c)
#pragma unroll
        for (int t = 0; t < 2; ++t) {
            acc[t] = __builtin_amdgcn_mfma_f32_32x32x16_bf16(f.ah[c], f.bh[c][t], acc[t], 0, 0, 0);
            acc[t] = __builtin_amdgcn_mfma_f32_32x32x16_bf16(f.ah[c], f.bl[c][t], acc[t], 0, 0, 0);
            acc[t] = __builtin_amdgcn_mfma_f32_32x32x16_bf16(f.al[c], f.bh[c][t], acc[t], 0, 0, 0);
        }
}

// DEPTH-3 counted-vmcnt pipeline. Per iter:
//   wait vmcnt(12)  -> my stage-i loads landed (tail: 6, then 0)
//   s_barrier (B1)  -> every wave's stage-i loads landed
//   frag_read; lgkmcnt(0); sched_barrier
//   s_barrier (B2)  -> every wave done reading buf[i%3]; safe to overwrite
//   issue stage(i+3) into buf[i%3]; MFMA on registers
__device__ __forceinline__ void gemm_pipe(const unsigned short* __restrict__ Ah,
                                          const unsigned short* __restrict__ Bh,
                                          int nt0, int i0, int n, f32x16 acc[2],
                                          unsigned short* lds, int wave, int lane)
{
#pragma unroll
    for (int d = 0; d < DEPTH; ++d)
        gemm_stage(Ah, Bh, nt0, i0 + d, lds + d * LDSH, wave, lane);
    for (int i = 0; i < n; ++i) {
        unsigned short* buf = lds + (i % DEPTH) * LDSH;
        const int ahead = n - 1 - i;   // stages issued beyond i (capped at DEPTH-1)
        if (ahead >= 2)      asm volatile("s_waitcnt vmcnt(12)" ::: "memory");
        else if (ahead == 1) asm volatile("s_waitcnt vmcnt(6)" ::: "memory");
        else                 asm volatile("s_waitcnt vmcnt(0)" ::: "memory");
        __builtin_amdgcn_s_barrier();                 // B1
        Frags f;
        frag_read(buf, f, wave, lane);
        asm volatile("s_waitcnt lgkmcnt(0)" ::: "memory");
        __builtin_amdgcn_sched_barrier(0);
        __builtin_amdgcn_s_barrier();                 // B2
        __builtin_amdgcn_sched_barrier(0);
        if (i + DEPTH < n)
            gemm_stage(Ah, Bh, nt0, i0 + i + DEPTH, buf, wave, lane);
        frag_mfma(f, acc);
    }
}

__device__ __forceinline__ void cwrite(float* __restrict__ C, const f32x16 acc[2],
                                       int n0, int wave, int lane)
{
#pragma unroll
    for (int t = 0; t < 2; ++t)
#pragma unroll
        for (int q = 0; q < 16; ++q) {
            const int m = 32 * wave + (q & 3) + 8 * (q >> 2) + 4 * (lane >> 5);
            const int n = n0 + t * 32 + (lane & 31);
            C[(long)m * FH + n] = acc[t][q];
        }
}

// phase1: 192 blocks. job 0: A0a = x_t@U0 ; job 1: A0b = h0@V0 ; job 2: T1 = h1@V1
__global__ __launch_bounds__(256) void phase1(
    const unsigned short* __restrict__ xsw,  const unsigned short* __restrict__ U0sw,
    const unsigned short* __restrict__ h0sw, const unsigned short* __restrict__ V0sw,
    const unsigned short* __restrict__ h1sw, const unsigned short* __restrict__ V1sw,
    float* __restrict__ A0a, float* __restrict__ A0b, float* __restrict__ T1)
{
    __shared__ unsigned short lds[DEPTH * LDSH];
    const int tid = threadIdx.x, wave = tid >> 6, lane = tid & 63;
    const int nblk = blockIdx.x & 63, job = blockIdx.x >> 6;
    const int nt0 = nblk * 2, n0 = nblk * 64;
    const unsigned short* Ah = (job == 0) ? xsw  : (job == 1) ? h0sw : h1sw;
    const unsigned short* Bh = (job == 0) ? U0sw : (job == 1) ? V0sw : V1sw;
    float* C = (job == 0) ? A0a : (job == 1) ? A0b : T1;
    f32x16 acc[2];
#pragma unroll
    for (int t = 0; t < 2; ++t)
#pragma unroll
        for (int q = 0; q < 16; ++q) acc[t][q] = 0.0f;
    gemm_pipe(Ah, Bh, nt0, 0, 32, acc, lds, wave, lane);
    cwrite(C, acc, n0, wave, lane);
}

// phase2: 128 blocks, K-split. ks 0: A1a = h0@U1[k<512] ; ks 1: A1b = h0@U1[k>=512]
__global__ __launch_bounds__(256) void phase2(
    const unsigned short* __restrict__ h0sw, const unsigned short* __restrict__ U1sw,
    float* __restrict__ A1a, float* __restrict__ A1b)
{
    __shared__ unsigned short lds[DEPTH * LDSH];
    const int tid = threadIdx.x, wave = tid >> 6, lane = tid & 63;
    const int nblk = blockIdx.x & 63, ks = blockIdx.x >> 6;
    const int nt0 = nblk * 2, n0 = nblk * 64;
    f32x16 acc[2];
#pragma unroll
    for (int t = 0; t < 2; ++t)
#pragma unroll
        for (int q = 0; q < 16; ++q) acc[t][q] = 0.0f;
    gemm_pipe(h0sw, U1sw, nt0, ks * 16, 16, acc, lds, wave, lane);
    cwrite(ks ? A1b : A1a, acc, n0, wave, lane);
}

// split one fp32 value-row chunk into swizzled hi/lo planes (A layout)
__device__ __forceinline__ void split_to_Asw(const float v[8], unsigned short* __restrict__ sw,
                                             int b, int k8)
{
    ushort8 hh, ll;
#pragma unroll
    for (int j = 0; j < 8; ++j) {
        const unsigned short h = f2bf(v[j]);
        hh[j] = h;
        ll[j] = f2bf(v[j] - bf2f(h));
    }
    const int kc = k8 >> 1, half = k8 & 1;
    const int l = half * 32 + (b & 31), rt = b >> 5;
    const long o = ((long)(kc * 4 + rt) * 64 + l) * 8;
    *(ushort8*)(sw + o) = hh;
    *(ushort8*)(sw + APL + o) = ll;
}

// cell0: gates from A0a+A0b+b0 -> c0, h0 (fp32) + h0sw. 128 blocks x 128 thr.
__global__ __launch_bounds__(128) void cell0(
    const float* __restrict__ A0a, const float* __restrict__ A0b,
    const float* __restrict__ b0,
    float* __restrict__ c0, float* __restrict__ h0,
    unsigned short* __restrict__ h0sw, const float* __restrict__ u_rnd)
{
    const int b = blockIdx.x, k8 = threadIdx.x;
    const long gb = (long)b * FH + k8 * 8;
    const long sb = (long)b * HSZ + k8 * 8;
    const float u = u_rnd[b];
    float hn[8];
#pragma unroll
    for (int half = 0; half < 2; ++half) {
        const int j0 = half * 4;
        const float4 aia = *(const float4*)(A0a + gb + j0);
        const float4 aib = *(const float4*)(A0b + gb + j0);
        const float4 afa = *(const float4*)(A0a + gb + HSZ + j0);
        const float4 afb = *(const float4*)(A0b + gb + HSZ + j0);
        const float4 aga = *(const float4*)(A0a + gb + 2 * HSZ + j0);
        const float4 agb = *(const float4*)(A0b + gb + 2 * HSZ + j0);
        const float4 aoa = *(const float4*)(A0a + gb + 3 * HSZ + j0);
        const float4 aob = *(const float4*)(A0b + gb + 3 * HSZ + j0);
        const float4 bi = *(const float4*)(b0 + k8 * 8 + j0);
        const float4 bf = *(const float4*)(b0 + HSZ + k8 * 8 + j0);
        const float4 bg = *(const float4*)(b0 + 2 * HSZ + k8 * 8 + j0);
        const float4 bo = *(const float4*)(b0 + 3 * HSZ + k8 * 8 + j0);
        float4 cv = *(const float4*)(c0 + sb + j0);
        const float4 hv = *(const float4*)(h0 + sb + j0);
        float4 cn, hq;
#pragma unroll
        for (int j = 0; j < 4; ++j) {
            const float I = sigm_(((const float*)&aia)[j] + ((const float*)&aib)[j] + ((const float*)&bi)[j]);
            const float F = sigm_(((const float*)&afa)[j] + ((const float*)&afb)[j] + ((const float*)&bf)[j]);
            const float G = tanhf(((const float*)&aga)[j] + ((const float*)&agb)[j] + ((const float*)&bg)[j]);
            const float O = sigm_(((const float*)&aoa)[j] + ((const float*)&aob)[j] + ((const float*)&bo)[j]);
            const float c = fmaf(F, ((const float*)&cv)[j], I * G);
            ((float*)&cn)[j] = c;
            const float h = u * (O * tanhf(c)) + (1.0f - u) * ((const float*)&hv)[j];
            ((float*)&hq)[j] = h;
            hn[j0 + j] = h;
        }
        *(float4*)(c0 + sb + j0) = cn;
        *(float4*)(h0 + sb + j0) = hq;
    }
    split_to_Asw(hn, h0sw, b, k8);
}

// cell1: gates from A1a+A1b+T1+b1 -> c1, h1, out, h1sw; fused skip-dot + u
// update (blocks [0,128)); blocks [128,256) swizzle x_{t+1}.
__global__ __launch_bounds__(128) void cell1(
    const float* __restrict__ A1a, const float* __restrict__ A1b,
    const float* __restrict__ T1, const float* __restrict__ b1,
    float* __restrict__ c1, float* __restrict__ h1,
    unsigned short* __restrict__ h1sw,
    float* __restrict__ u_t, float* __restrict__ u_rnd,
    const float* __restrict__ skip_w, const float* __restrict__ skip_b,
    float* __restrict__ out, int t,
    const float* __restrict__ x, unsigned short* __restrict__ xsw)
{
    __shared__ float red[2];
    if (blockIdx.x < 128) {
        const int b = blockIdx.x, k8 = threadIdx.x;
        const long gb = (long)b * FH + k8 * 8;
        const long sb = (long)b * HSZ + k8 * 8;
        const float u = u_rnd[b];
        const float ut_old = u_t[b];
        float hn[8];
        float part = 0.0f;
#pragma unroll
        for (int half = 0; half < 2; ++half) {
            const int j0 = half * 4;
            const float4 aia = *(const float4*)(A1a + gb + j0);
            const float4 aib = *(const float4*)(A1b + gb + j0);
            const float4 ait = *(const float4*)(T1 + gb + j0);
            const float4 afa = *(const float4*)(A1a + gb + HSZ + j0);
            const float4 afb = *(const float4*)(A1b + gb + HSZ + j0);
            const float4 aft = *(const float4*)(T1 + gb + HSZ + j0);
            const float4 aga = *(const float4*)(A1a + gb + 2 * HSZ + j0);
            const float4 agb = *(const float4*)(A1b + gb + 2 * HSZ + j0);
            const float4 agt = *(const float4*)(T1 + gb + 2 * HSZ + j0);
            const float4 aoa = *(const float4*)(A1a + gb + 3 * HSZ + j0);
            const float4 aob = *(const float4*)(A1b + gb + 3 * HSZ + j0);
            const float4 aot = *(const float4*)(T1 + gb + 3 * HSZ + j0);
            const float4 bi = *(const float4*)(b1 + k8 * 8 + j0);
            const float4 bf = *(const float4*)(b1 + HSZ + k8 * 8 + j0);
            const float4 bg = *(const float4*)(b1 + 2 * HSZ + k8 * 8 + j0);
            const float4 bo = *(const float4*)(b1 + 3 * HSZ + k8 * 8 + j0);
            float4 cv = *(const float4*)(c1 + sb + j0);
            const float4 hv = *(const float4*)(h1 + sb + j0);
            const float4 sw4 = *(const float4*)(skip_w + k8 * 8 + j0);
            float4 cn, hq;
#pragma unroll
            for (int j = 0; j < 4; ++j) {
                const float I = sigm_(((const float*)&aia)[j] + ((const float*)&aib)[j] + ((const float*)&ait)[j] + ((const float*)&bi)[j]);
                const float F = sigm_(((const float*)&afa)[j] + ((const float*)&afb)[j] + ((const float*)&aft)[j] + ((const float*)&bf)[j]);
                const float G = tanhf(((const float*)&aga)[j] + ((const float*)&agb)[j] + ((const float*)&agt)[j] + ((const float*)&bg)[j]);
                const float O = sigm_(((const float*)&aoa)[j] + ((const float*)&aob)[j] + ((const float*)&aot)[j] + ((const float*)&bo)[j]);
                const float c = fmaf(F, ((const float*)&cv)[j], I * G);
                ((float*)&cn)[j] = c;
                part = fmaf(c, ((const float*)&sw4)[j], part);
                const float h = u * (O * tanhf(c)) + (1.0f - u) * ((const float*)&hv)[j];
                ((float*)&hq)[j] = h;
                hn[j0 + j] = h;
            }
            *(float4*)(c1 + sb + j0) = cn;
            *(float4*)(h1 + sb + j0) = hq;
            *(float4*)(out + ((long)b * SS + t) * HSZ + k8 * 8 + j0) = hq;
        }
        split_to_Asw(hn, h1sw, b, k8);
#pragma unroll
        for (int off = 32; off > 0; off >>= 1) part += __shfl_down(part, off, 64);
        const int wave = threadIdx.x >> 6;
        if ((threadIdx.x & 63) == 0) red[wave] = part;
        __syncthreads();
        if (threadIdx.x == 0) {
            const float z = red[0] + red[1];
            const float cu = sigm_(z + skip_b[0]);
            const float nut = u * cu + (1.0f - u) * (ut_old + fminf(cu, 1.0f - ut_old));
            u_t[b] = nut;
            u_rnd[b] = rintf(nut);
        }
    } else {
        // swizzle x for step t+1
        if (t + 1 >= SS) return;
        const int idx = (blockIdx.x - 128) * 128 + threadIdx.x;
        const int b = idx >> 7, k8 = idx & 127;
        const float* xr = x + ((long)b * SS + (t + 1)) * HSZ + k8 * 8;
        float v[8];
        const float4 v0 = *(const float4*)(xr);
        const float4 v1 = *(const float4*)(xr + 4);
#pragma unroll
        for (int j = 0; j < 4; ++j) { v[j] = ((const float*)&v0)[j]; v[4 + j] = ((const float*)&v1)[j]; }
        split_to_Asw(v, xsw, b, k8);
    }
}

// weight split+swizzle: one thread per (w, nt, kc, lane)
__global__ __launch_bounds__(256) void prep_w(
    const float* __restrict__ U0, const float* __restrict__ V0,
    const float* __restrict__ U1, const float* __restrict__ V1,
    unsigned short* __restrict__ U0sw, unsigned short* __restrict__ V0sw,
    unsigned short* __restrict__ U1sw, unsigned short* __restrict__ V1sw)
{
    const long gid = (long)blockIdx.x * 256 + threadIdx.x;  // 4 * 524288
    const int w = (int)(gid >> 19);
    const int r = (int)(gid & 524287);                      // nt*4096 + kc*64 + l
    const int nt = r >> 12;
    const int kc = (r >> 6) & 63;
    const int l = r & 63;
    const float* W = (w == 0) ? U0 : (w == 1) ? V0 : (w == 2) ? U1 : V1;
    unsigned short* O = (w == 0) ? U0sw : (w == 1) ? V0sw : (w == 2) ? U1sw : V1sw;
    const int n = nt * 32 + (l & 31);
    const int k0 = kc * 16 + (l >> 5) * 8;
    ushort8 hh, ll;
#pragma unroll
    for (int j = 0; j < 8; ++j) {
        const float f = W[(long)(k0 + j) * FH + n];
        const unsigned short h = f2bf(f);
        hh[j] = h;
        ll[j] = f2bf(f - bf2f(h));
    }
    const long ob = (long)r * 8;
    *(ushort8*)(O + ob) = hh;
    *(ushort8*)(O + BPL + ob) = ll;
}

// init: zero fp32 states, zero h0sw/h1sw, u=1, swizzle x_0
__global__ __launch_bounds__(256) void init_k(
    float* __restrict__ states, float* __restrict__ swz_f,
    float* __restrict__ u_t, float* __restrict__ u_rnd,
    const float* __restrict__ x, unsigned short* __restrict__ xsw)
{
    const int blk = blockIdx.x;
    const float4 z = {0.0f, 0.0f, 0.0f, 0.0f};
    if (blk < 512) {
        *(float4*)(states + ((long)blk * 256 + threadIdx.x) * 4) = z;
    } else if (blk < 768) {
        *(float4*)(swz_f + ((long)(blk - 512) * 256 + threadIdx.x) * 4) = z;
    } else {
        if (blk == 768 && threadIdx.x < 128) { u_t[threadIdx.x] = 1.0f; u_rnd[threadIdx.x] = 1.0f; }
        const int idx = (blk - 768) * 256 + threadIdx.x;
        const int b = idx >> 7, k8 = idx & 127;
        const float* xr = x + (long)b * SS * HSZ + k8 * 8;
        float v[8];
        const float4 v0 = *(const float4*)(xr);
        const float4 v1 = *(const float4*)(xr + 4);
#pragma unroll
        for (int j = 0; j < 4; ++j) { v[j] = ((const float*)&v0)[j]; v[4 + j] = ((const float*)&v1)[j]; }
        split_to_Asw(v, xsw, b, k8);
    }
}

extern "C" void kernel_launch(void* const* d_in, const int* in_sizes, int n_in,
                              void* d_out, int out_size, void* d_ws, size_t ws_size,
                              hipStream_t stream)
{
    const float* x      = (const float*)d_in[0];
    const float* U0     = (const float*)d_in[1];
    const float* V0     = (const float*)d_in[2];
    const float* b0     = (const float*)d_in[3];
    const float* U1     = (const float*)d_in[4];
    const float* V1     = (const float*)d_in[5];
    const float* b1     = (const float*)d_in[6];
    const float* skip_w = (const float*)d_in[7];
    const float* skip_b = (const float*)d_in[8];
    float* out = (float*)d_out;

    float* ws = (float*)d_ws;
    float* states = ws;                 // h0,c0,h1,c1 : 4*131072 floats
    float* h0 = ws;
    float* c0 = ws + 131072;
    float* h1 = ws + 262144;
    float* c1 = ws + 393216;
    float* A0a = ws + 524288;           // each 128x4096 fp32
    float* A0b = ws + 1048576;
    float* T1  = ws + 1572864;
    // A1a/A1b alias A0a/A0b: cell0 fully consumes A0a/A0b before phase2 writes
    // (stream-ordered), so the round-1 workspace footprint is preserved.
    float* A1a = A0a;
    float* A1b = A0b;
    float* u_t   = ws + 2097152;        // 128
    float* u_rnd = ws + 2097280;        // 128
    unsigned short* usbase = (unsigned short*)(ws + 2097664);  // 16B-aligned
    unsigned short* xsw  = usbase;                  // 2*APL ushorts
    unsigned short* h0sw = usbase + 262144;
    unsigned short* h1sw = usbase + 524288;
    unsigned short* U0sw = usbase + 786432;         // each 2*BPL ushorts
    unsigned short* V0sw = U0sw + 8388608;
    unsigned short* U1sw = V0sw + 8388608;
    unsigned short* V1sw = U1sw + 8388608;

    prep_w<<<8192, 256, 0, stream>>>(U0, V0, U1, V1, U0sw, V0sw, U1sw, V1sw);
    init_k<<<832, 256, 0, stream>>>(states, (float*)h0sw /* h0sw+h1sw zeroed */,
                                    u_t, u_rnd, x, xsw);

    for (int t = 0; t < SS; ++t) {
        phase1<<<192, 256, 0, stream>>>(xsw, U0sw, h0sw, V0sw, h1sw, V1sw, A0a, A0b, T1);
        cell0<<<128, 128, 0, stream>>>(A0a, A0b, b0, c0, h0, h0sw, u_rnd);
        phase2<<<128, 256, 0, stream>>>(h0sw, U1sw, A1a, A1b);
        cell1<<<256, 128, 0, stream>>>(A1a, A1b, T1, b1, c1, h1, h1sw, u_t, u_rnd,
                                       skip_w, skip_b, out, t, x, xsw);
    }
}